// Round 2
// baseline (584.643 us; speedup 1.0000x reference)
//
#include <hip/hip_runtime.h>
#include <hip/hip_bf16.h>

// Problem constants
constexpr int B_   = 8;
constexpr int D_   = 1024;
constexpr int T_   = 512;
constexpr int HID_ = 256;
constexpr int NH_  = 4;
constexpr int NL_  = 2;
constexpr int OUT_ = 64;
constexpr float ALPHA_ = 0.2f;
constexpr float EPS_   = 1e-5f;
constexpr int M_ = B_ * D_;      // 8192 rows
constexpr int DT_ = D_ * T_;     // 524288

// ---------------------------------------------------------------------------
// 1) Imputation: pos_mean over batch, X_mean = X*m + (1-m)*pos_mean
// ---------------------------------------------------------------------------
__global__ __launch_bounds__(256) void impute_k(const float* __restrict__ X,
                                                const float* __restrict__ Mk,
                                                float* __restrict__ Xm) {
    int idx = blockIdx.x * 256 + threadIdx.x;   // over D*T
    float x[B_], m[B_];
    float s = 0.f, c = 0.f;
#pragma unroll
    for (int b = 0; b < B_; b++) {
        x[b] = X[(size_t)b * DT_ + idx];
        m[b] = Mk[(size_t)b * DT_ + idx];
        s += x[b] * m[b];
        c += m[b];
    }
    float pm = s / (c + 1e-10f);
#pragma unroll
    for (int b = 0; b < B_; b++) {
        Xm[(size_t)b * DT_ + idx] = x[b] * m[b] + (1.f - m[b]) * pm;
    }
}

// ---------------------------------------------------------------------------
// 2) Pack gat_W[l] (NH,HID,OUT) -> Wcat[l] (HID, NH*OUT) so hW is one GEMM
// ---------------------------------------------------------------------------
__global__ __launch_bounds__(256) void pack_w_k(const float* __restrict__ gatW,
                                                float* __restrict__ Wcat) {
    int idx = blockIdx.x * 256 + threadIdx.x;   // over NL*HID*NH*OUT = 131072
    int l = idx >> 16;
    int rem = idx & 65535;
    int k = rem >> 8;
    int j = rem & 255;
    int h = j >> 6;
    int e = j & 63;
    Wcat[idx] = gatW[(((size_t)(l * NH_ + h) * HID_) + k) * OUT_ + e];
}

// ---------------------------------------------------------------------------
// 3) Generic fp32 GEMM: C[M,N] = A[M,K] @ B[K,N] (+ bias). BM=128 BN=64 BK=16
//    CONCAT: A[m,k] = k<T ? A0[m*T+k] : A1[m*T+k-T]
// ---------------------------------------------------------------------------
template <bool CONCAT>
__global__ __launch_bounds__(256) void gemm_k(const float* __restrict__ A0,
                                              const float* __restrict__ A1,
                                              const float* __restrict__ Bm,
                                              const float* __restrict__ bias,
                                              float* __restrict__ C,
                                              int Msz, int Nsz, int Ksz) {
    __shared__ float As[16][128];
    __shared__ float Bs[16][64];
    int tid = threadIdx.x;
    int bx = blockIdx.x, by = blockIdx.y;
    int tx = tid & 15;        // n dir (x4)
    int ty = tid >> 4;        // m dir (x8)
    int rowbase = by * 128;
    int colbase = bx * 64;
    float acc[8][4] = {};

    for (int kt = 0; kt < Ksz; kt += 16) {
        // A tile: 128x16 floats = 512 float4; 2 per thread
#pragma unroll
        for (int i = 0; i < 2; i++) {
            int s = tid * 2 + i;       // 0..511
            int r = s >> 2;            // 0..127
            int c4 = (s & 3) * 4;      // 0,4,8,12
            int gk = kt + c4;
            float4 v;
            if constexpr (CONCAT) {
                if (gk < T_) v = *(const float4*)(A0 + (size_t)(rowbase + r) * T_ + gk);
                else         v = *(const float4*)(A1 + (size_t)(rowbase + r) * T_ + gk - T_);
            } else {
                v = *(const float4*)(A0 + (size_t)(rowbase + r) * Ksz + gk);
            }
            As[c4 + 0][r] = v.x;
            As[c4 + 1][r] = v.y;
            As[c4 + 2][r] = v.z;
            As[c4 + 3][r] = v.w;
        }
        // B tile: 16x64 floats = 256 float4; 1 per thread
        {
            int kk = tid >> 4;
            int n4 = (tid & 15) * 4;
            float4 v = *(const float4*)(Bm + (size_t)(kt + kk) * Nsz + colbase + n4);
            *(float4*)&Bs[kk][n4] = v;
        }
        __syncthreads();
#pragma unroll
        for (int kk = 0; kk < 16; kk++) {
            float a[8], b[4];
            *(float4*)&a[0] = *(const float4*)&As[kk][ty * 8];
            *(float4*)&a[4] = *(const float4*)&As[kk][ty * 8 + 4];
            *(float4*)&b[0] = *(const float4*)&Bs[kk][tx * 4];
#pragma unroll
            for (int i = 0; i < 8; i++)
#pragma unroll
                for (int j = 0; j < 4; j++)
                    acc[i][j] += a[i] * b[j];
        }
        __syncthreads();
    }
#pragma unroll
    for (int i = 0; i < 8; i++) {
        int r = rowbase + ty * 8 + i;
#pragma unroll
        for (int j = 0; j < 4; j++) {
            int cidx = colbase + tx * 4 + j;
            float v = acc[i][j] + (bias ? bias[cidx] : 0.f);
            C[(size_t)r * Nsz + cidx] = v;
        }
    }
}

// ---------------------------------------------------------------------------
// 4) s_l, s_r, rowmax(s_r) per (b,h). grid = 32 blocks of 256 threads.
// ---------------------------------------------------------------------------
__global__ __launch_bounds__(256) void slr_k(const float* __restrict__ hw,
                                             const float* __restrict__ gat_a,
                                             int l,
                                             float* __restrict__ s_l,
                                             float* __restrict__ s_r,
                                             float* __restrict__ rmax) {
    int bh = blockIdx.x;
    int b = bh >> 2, h = bh & 3;
    __shared__ float al[OUT_], ar[OUT_];
    __shared__ float red[256];
    if (threadIdx.x < OUT_)
        al[threadIdx.x] = gat_a[(size_t)(l * NH_ + h) * 2 * OUT_ + threadIdx.x];
    else if (threadIdx.x < 2 * OUT_)
        ar[threadIdx.x - OUT_] = gat_a[(size_t)(l * NH_ + h) * 2 * OUT_ + threadIdx.x];
    __syncthreads();
    float lmax = -1e30f;
    for (int n = threadIdx.x; n < D_; n += 256) {
        const float* row = hw + (size_t)(b * D_ + n) * HID_ + h * OUT_;
        float sl = 0.f, sr = 0.f;
#pragma unroll 8
        for (int e = 0; e < OUT_; e++) {
            float v = row[e];
            sl += v * al[e];
            sr += v * ar[e];
        }
        s_l[bh * D_ + n] = sl;
        s_r[bh * D_ + n] = sr;
        lmax = fmaxf(lmax, sr);
    }
    red[threadIdx.x] = lmax;
    __syncthreads();
    for (int s = 128; s > 0; s >>= 1) {
        if (threadIdx.x < s) red[threadIdx.x] = fmaxf(red[threadIdx.x], red[threadIdx.x + s]);
        __syncthreads();
    }
    if (threadIdx.x == 0) rmax[bh] = red[0];
}

// ---------------------------------------------------------------------------
// 5) Attention (flash-style, no S matrix). grid (32 bh, 8 rowblocks), 256 thr.
//    Each wave: 32 rows in registers; m-chunks of 64 staged in LDS.
// ---------------------------------------------------------------------------
__global__ __launch_bounds__(256) void attn_k(const float* __restrict__ hw,
                                              const float* __restrict__ sl_g,
                                              const float* __restrict__ sr_g,
                                              const float* __restrict__ rmax_g,
                                              float* __restrict__ hnew) {
    int bh = blockIdx.x;
    int b = bh >> 2, h = bh & 3;
    int tid = threadIdx.x;
    int wave = tid >> 6, lane = tid & 63;

    __shared__ float srs[D_];            // 4 KB
    __shared__ float hwc[64][64];        // 16 KB
    __shared__ float pbuf[4][8][64][4];  // 32 KB  [wave][rb][m][rl]

    for (int i = tid; i < D_; i += 256) srs[i] = sr_g[bh * D_ + i];
    float rm = rmax_g[bh];
    int rowbase = blockIdx.y * 128 + wave * 32;

    float sl[32], Mn[32], acc[32], den[32];
#pragma unroll
    for (int r = 0; r < 32; r++) {
        float s = sl_g[bh * D_ + rowbase + r];
        sl[r] = s;
        float x = s + rm;
        Mn[r] = (x >= 0.f) ? x : ALPHA_ * x;
        acc[r] = 0.f;
        den[r] = 0.f;
    }
    __syncthreads();

    for (int mc = 0; mc < D_; mc += 64) {
        // stage hW[mc..mc+63][0..63] for this head
#pragma unroll
        for (int i = 0; i < 4; i++) {
            int s = tid + i * 256;     // 0..1023 float4 slots
            int mm = s >> 4;           // 0..63
            int e4 = (s & 15) * 4;
            float4 v = *(const float4*)(hw + (size_t)(b * D_ + mc + mm) * HID_ + h * OUT_ + e4);
            *(float4*)&hwc[mm][e4] = v;
        }
        __syncthreads();
        // phase A: lane handles m = mc + lane; p for all 32 rows
        {
            float sr = srs[mc + lane];
#pragma unroll
            for (int rb = 0; rb < 8; rb++) {
                float4 pv;
#pragma unroll
                for (int rl = 0; rl < 4; rl++) {
                    int r = rb * 4 + rl;
                    float x = sl[r] + sr;
                    float e = (x >= 0.f) ? x : ALPHA_ * x;
                    float p = __expf(e - Mn[r]);
                    ((float*)&pv)[rl] = p;
                    den[r] += p;
                }
                *(float4*)&pbuf[wave][rb][lane][0] = pv;
            }
        }
        __syncthreads();
        // phase B: lane = output channel e; accumulate 32 rows over 64 m
        for (int j = 0; j < 64; j++) {
            float hv = hwc[j][lane];
#pragma unroll
            for (int rb = 0; rb < 8; rb++) {
                float4 p4 = *(const float4*)&pbuf[wave][rb][j][0];
                acc[rb * 4 + 0] += p4.x * hv;
                acc[rb * 4 + 1] += p4.y * hv;
                acc[rb * 4 + 2] += p4.z * hv;
                acc[rb * 4 + 3] += p4.w * hv;
            }
        }
        __syncthreads();
    }
    // finish: reduce denominators across lanes, write out
#pragma unroll
    for (int r = 0; r < 32; r++) {
        float dsum = den[r];
#pragma unroll
        for (int off = 32; off > 0; off >>= 1) dsum += __shfl_down(dsum, off, 64);
        dsum = __shfl(dsum, 0, 64);
        hnew[(size_t)(b * D_ + rowbase + r) * HID_ + h * OUT_ + lane] = acc[r] / dsum;
    }
}

// ---------------------------------------------------------------------------
// 6) h = LayerNorm(h + hnew) * g + b   (row = 256 wide, one block per row)
// ---------------------------------------------------------------------------
__global__ __launch_bounds__(256) void addln_k(float* __restrict__ h,
                                               const float* __restrict__ hn,
                                               const float* __restrict__ g,
                                               const float* __restrict__ bb) {
    int row = blockIdx.x;
    int c = threadIdx.x;
    float v = h[(size_t)row * HID_ + c] + hn[(size_t)row * HID_ + c];
    __shared__ float red[256];
    red[c] = v;
    __syncthreads();
    for (int s = 128; s > 0; s >>= 1) {
        if (c < s) red[c] += red[c + s];
        __syncthreads();
    }
    float mu = red[0] * (1.f / HID_);
    __syncthreads();
    float d = v - mu;
    red[c] = d * d;
    __syncthreads();
    for (int s = 128; s > 0; s >>= 1) {
        if (c < s) red[c] += red[c + s];
        __syncthreads();
    }
    float var = red[0] * (1.f / HID_);
    h[(size_t)row * HID_ + c] = d * rsqrtf(var + EPS_) * g[c] + bb[c];
}

// ---------------------------------------------------------------------------
extern "C" void kernel_launch(void* const* d_in, const int* in_sizes, int n_in,
                              void* d_out, int out_size, void* d_ws, size_t ws_size,
                              hipStream_t stream) {
    const float* X_obs = (const float*)d_in[0];
    const float* mask  = (const float*)d_in[1];
    const float* W_in  = (const float*)d_in[2];
    const float* b_in  = (const float*)d_in[3];
    const float* gat_W = (const float*)d_in[4];
    const float* gat_a = (const float*)d_in[5];
    const float* ln_g  = (const float*)d_in[6];
    const float* ln_b  = (const float*)d_in[7];
    const float* W_out = (const float*)d_in[8];
    const float* b_out = (const float*)d_in[9];
    float* out = (float*)d_out;    // reference output dtype is float32

    float* ws    = (float*)d_ws;
    float* Xmean = ws;                          // 4,194,304
    float* hbuf  = Xmean + (size_t)M_ * T_;     // 2,097,152
    float* hwb   = hbuf + (size_t)M_ * HID_;    // 2,097,152
    float* slb   = hwb + (size_t)M_ * HID_;     // 32,768
    float* srb   = slb + B_ * NH_ * D_;         // 32,768
    float* rmx   = srb + B_ * NH_ * D_;         // 32
    float* Wcat  = rmx + 64;                    // 131,072
    float* hnew  = Xmean;                       // reuse Xmean after h is built

    impute_k<<<DT_ / 256, 256, 0, stream>>>(X_obs, mask, Xmean);
    pack_w_k<<<(NL_ * HID_ * NH_ * OUT_) / 256, 256, 0, stream>>>(gat_W, Wcat);

    // h = [X_mean | mask] @ W_in + b_in   (8192 x 1024) @ (1024 x 256)
    gemm_k<true><<<dim3(HID_ / 64, M_ / 128), 256, 0, stream>>>(
        Xmean, mask, W_in, b_in, hbuf, M_, HID_, 2 * T_);

    for (int l = 0; l < NL_; l++) {
        // hW = h @ Wcat[l]   (8192 x 256) @ (256 x 256)
        gemm_k<false><<<dim3(HID_ / 64, M_ / 128), 256, 0, stream>>>(
            hbuf, nullptr, Wcat + (size_t)l * HID_ * HID_, nullptr, hwb, M_, HID_, HID_);
        slr_k<<<B_ * NH_, 256, 0, stream>>>(hwb, gat_a, l, slb, srb, rmx);
        attn_k<<<dim3(B_ * NH_, D_ / 128), 256, 0, stream>>>(hwb, slb, srb, rmx, hnew);
        addln_k<<<M_, 256, 0, stream>>>(hbuf, hnew, ln_g + (size_t)l * HID_,
                                        ln_b + (size_t)l * HID_);
    }

    // out = h @ W_out + b_out  (8192 x 256) @ (256 x 512), fp32 out
    gemm_k<false><<<dim3(T_ / 64, M_ / 128), 256, 0, stream>>>(
        hbuf, nullptr, W_out, b_out, out, M_, T_, HID_);
}

// Round 3
// 419.165 us; speedup vs baseline: 1.3948x; 1.3948x over previous
//
#include <hip/hip_runtime.h>
#include <hip/hip_bf16.h>

// Problem constants
constexpr int B_   = 8;
constexpr int D_   = 1024;
constexpr int T_   = 512;
constexpr int HID_ = 256;
constexpr int NH_  = 4;
constexpr int NL_  = 2;
constexpr int OUT_ = 64;
constexpr float ALPHA_ = 0.2f;
constexpr float EPS_   = 1e-5f;
constexpr int M_ = B_ * D_;      // 8192 rows
constexpr int DT_ = D_ * T_;     // 524288
constexpr int KIN_ = 2 * T_;     // 1024

typedef __attribute__((ext_vector_type(8))) short short8;   // 8 bf16 (4 VGPRs)
typedef __attribute__((ext_vector_type(4))) float floatx4;  // 4 fp32 acc

__device__ __forceinline__ unsigned short f2bf(float f) {
    unsigned int u = __float_as_uint(f);
    unsigned int r = u + 0x7fffu + ((u >> 16) & 1u);   // round-to-nearest-even
    return (unsigned short)(r >> 16);
}

// ---------------------------------------------------------------------------
// 1) Imputation -> packed bf16 concat matrix A_in[M][1024] = [X_mean | mask]
// ---------------------------------------------------------------------------
__global__ __launch_bounds__(256) void impute_k(const float* __restrict__ X,
                                                const float* __restrict__ Mk,
                                                unsigned short* __restrict__ Ain) {
    int idx = blockIdx.x * 256 + threadIdx.x;   // over D*T
    int t = idx & (T_ - 1);
    int d = idx >> 9;                            // T_=512
    float x[B_], m[B_];
    float s = 0.f, c = 0.f;
#pragma unroll
    for (int b = 0; b < B_; b++) {
        x[b] = X[(size_t)b * DT_ + idx];
        m[b] = Mk[(size_t)b * DT_ + idx];
        s += x[b] * m[b];
        c += m[b];
    }
    float pm = s / (c + 1e-10f);
#pragma unroll
    for (int b = 0; b < B_; b++) {
        float xm = x[b] * m[b] + (1.f - m[b]) * pm;
        size_t row = (size_t)b * D_ + d;
        Ain[row * KIN_ + t]      = f2bf(xm);
        Ain[row * KIN_ + T_ + t] = f2bf(m[b]);
    }
}

// ---------------------------------------------------------------------------
// 2a) Generic transpose+convert: src fp32 [K][N] -> dst bf16 [N][K]
// ---------------------------------------------------------------------------
__global__ __launch_bounds__(256) void tconv_k(const float* __restrict__ src,
                                               unsigned short* __restrict__ dst,
                                               int K, int N) {
    int idx = blockIdx.x * 256 + threadIdx.x;
    if (idx >= K * N) return;
    int n = idx / K, k = idx - n * K;
    dst[idx] = f2bf(src[(size_t)k * N + n]);
}

// 2b) gat_W (NL,NH,HID,OUT) -> Wcat_t[l][n=NH*OUT][k=HID] bf16 (transposed)
__global__ __launch_bounds__(256) void wcat_t_k(const float* __restrict__ gatW,
                                                unsigned short* __restrict__ Wt) {
    int idx = blockIdx.x * 256 + threadIdx.x;   // over NL*256*256 = 131072
    int l = idx >> 16;
    int n = (idx >> 8) & 255;
    int k = idx & 255;
    int h = n >> 6, e = n & 63;
    Wt[idx] = f2bf(gatW[(((size_t)(l * NH_ + h) * HID_) + k) * OUT_ + e]);
}

// ---------------------------------------------------------------------------
// 3) bf16 MFMA GEMM: C[M,N] = A[M,K] @ Bt[N,K]^T (+bias). BM=128 BN=64 BK=32.
//    4 waves; wave w computes rows w*32..w*32+31 x all 64 cols (2x4 MFMA tiles)
// ---------------------------------------------------------------------------
template <bool WB>   // also emit bf16 copy of C
__global__ __launch_bounds__(256) void gemm_bf16_k(
        const unsigned short* __restrict__ A,    // M x K bf16
        const unsigned short* __restrict__ Bt,   // N x K bf16 (B transposed)
        const float* __restrict__ bias,          // N or null
        float* __restrict__ C,                   // M x N fp32
        unsigned short* __restrict__ Cb,         // M x N bf16 (if WB)
        int Msz, int Nsz, int Ksz) {
    __shared__ __align__(16) unsigned short As[128 * 32];  // [row][k] 8 KB
    __shared__ __align__(16) unsigned short Bs[64 * 32];   // [col][k] 4 KB
    int tid = threadIdx.x;
    int wave = tid >> 6, lane = tid & 63;
    int q = lane >> 4, r16 = lane & 15;
    int rowbase = blockIdx.y * 128;
    int colbase = blockIdx.x * 64;

    floatx4 acc[2][4];
#pragma unroll
    for (int i = 0; i < 2; i++)
#pragma unroll
        for (int j = 0; j < 4; j++) acc[i][j] = (floatx4)0.f;

    for (int kt = 0; kt < Ksz; kt += 32) {
        // stage A tile: 128 rows x 32 k = 512 16B-chunks, 2 per thread
#pragma unroll
        for (int i = 0; i < 2; i++) {
            int c = tid + i * 256;
            int row = c >> 2, off = (c & 3) * 8;
            *(uint4*)&As[c * 8] =
                *(const uint4*)&A[(size_t)(rowbase + row) * Ksz + kt + off];
        }
        // stage B tile: 64 cols x 32 k = 256 16B-chunks, 1 per thread
        {
            int n = tid >> 2, off = (tid & 3) * 8;
            *(uint4*)&Bs[tid * 8] =
                *(const uint4*)&Bt[(size_t)(colbase + n) * Ksz + kt + off];
        }
        __syncthreads();
        short8 a[2], b[4];
#pragma unroll
        for (int mi = 0; mi < 2; mi++)
            a[mi] = *(const short8*)&As[(wave * 32 + mi * 16 + r16) * 32 + q * 8];
#pragma unroll
        for (int ni = 0; ni < 4; ni++)
            b[ni] = *(const short8*)&Bs[(ni * 16 + r16) * 32 + q * 8];
#pragma unroll
        for (int mi = 0; mi < 2; mi++)
#pragma unroll
            for (int ni = 0; ni < 4; ni++)
                acc[mi][ni] = __builtin_amdgcn_mfma_f32_16x16x32_bf16(
                    a[mi], b[ni], acc[mi][ni], 0, 0, 0);
        __syncthreads();
    }
    // epilogue: C/D map col=lane&15, row=(lane>>4)*4+reg
#pragma unroll
    for (int mi = 0; mi < 2; mi++) {
#pragma unroll
        for (int rr = 0; rr < 4; rr++) {
            int row = rowbase + wave * 32 + mi * 16 + q * 4 + rr;
#pragma unroll
            for (int ni = 0; ni < 4; ni++) {
                int col = colbase + ni * 16 + r16;
                float v = acc[mi][ni][rr] + (bias ? bias[col] : 0.f);
                C[(size_t)row * Nsz + col] = v;
                if constexpr (WB) Cb[(size_t)row * Nsz + col] = f2bf(v);
            }
        }
    }
}

// ---------------------------------------------------------------------------
// 4) s_l, s_r, rowmax(s_r) per (b,h). grid = 32 blocks of 256 threads.
// ---------------------------------------------------------------------------
__global__ __launch_bounds__(256) void slr_k(const float* __restrict__ hw,
                                             const float* __restrict__ gat_a,
                                             int l,
                                             float* __restrict__ s_l,
                                             float* __restrict__ s_r,
                                             float* __restrict__ rmax) {
    int bh = blockIdx.x;
    int b = bh >> 2, h = bh & 3;
    __shared__ float al[OUT_], ar[OUT_];
    __shared__ float red[256];
    if (threadIdx.x < OUT_)
        al[threadIdx.x] = gat_a[(size_t)(l * NH_ + h) * 2 * OUT_ + threadIdx.x];
    else if (threadIdx.x < 2 * OUT_)
        ar[threadIdx.x - OUT_] = gat_a[(size_t)(l * NH_ + h) * 2 * OUT_ + threadIdx.x];
    __syncthreads();
    float lmax = -1e30f;
    for (int n = threadIdx.x; n < D_; n += 256) {
        const float* row = hw + (size_t)(b * D_ + n) * HID_ + h * OUT_;
        float sl = 0.f, sr = 0.f;
#pragma unroll 8
        for (int e = 0; e < OUT_; e++) {
            float v = row[e];
            sl += v * al[e];
            sr += v * ar[e];
        }
        s_l[bh * D_ + n] = sl;
        s_r[bh * D_ + n] = sr;
        lmax = fmaxf(lmax, sr);
    }
    red[threadIdx.x] = lmax;
    __syncthreads();
    for (int s = 128; s > 0; s >>= 1) {
        if (threadIdx.x < s) red[threadIdx.x] = fmaxf(red[threadIdx.x], red[threadIdx.x + s]);
        __syncthreads();
    }
    if (threadIdx.x == 0) rmax[bh] = red[0];
}

// ---------------------------------------------------------------------------
// 5) Attention (flash-style, no S matrix). grid (32 bh, 8 rowblocks), 256 thr.
// ---------------------------------------------------------------------------
__global__ __launch_bounds__(256) void attn_k(const float* __restrict__ hw,
                                              const float* __restrict__ sl_g,
                                              const float* __restrict__ sr_g,
                                              const float* __restrict__ rmax_g,
                                              float* __restrict__ hnew) {
    int bh = blockIdx.x;
    int b = bh >> 2, h = bh & 3;
    int tid = threadIdx.x;
    int wave = tid >> 6, lane = tid & 63;

    __shared__ float srs[D_];            // 4 KB
    __shared__ float hwc[64][64];        // 16 KB
    __shared__ float pbuf[4][8][64][4];  // 32 KB  [wave][rb][m][rl]

    for (int i = tid; i < D_; i += 256) srs[i] = sr_g[bh * D_ + i];
    float rm = rmax_g[bh];
    int rowbase = blockIdx.y * 128 + wave * 32;

    float sl[32], Mn[32], acc[32], den[32];
#pragma unroll
    for (int r = 0; r < 32; r++) {
        float s = sl_g[bh * D_ + rowbase + r];
        sl[r] = s;
        float x = s + rm;
        Mn[r] = (x >= 0.f) ? x : ALPHA_ * x;
        acc[r] = 0.f;
        den[r] = 0.f;
    }
    __syncthreads();

    for (int mc = 0; mc < D_; mc += 64) {
#pragma unroll
        for (int i = 0; i < 4; i++) {
            int s = tid + i * 256;
            int mm = s >> 4;
            int e4 = (s & 15) * 4;
            float4 v = *(const float4*)(hw + (size_t)(b * D_ + mc + mm) * HID_ + h * OUT_ + e4);
            *(float4*)&hwc[mm][e4] = v;
        }
        __syncthreads();
        {
            float sr = srs[mc + lane];
#pragma unroll
            for (int rb = 0; rb < 8; rb++) {
                float4 pv;
#pragma unroll
                for (int rl = 0; rl < 4; rl++) {
                    int r = rb * 4 + rl;
                    float x = sl[r] + sr;
                    float e = (x >= 0.f) ? x : ALPHA_ * x;
                    float p = __expf(e - Mn[r]);
                    ((float*)&pv)[rl] = p;
                    den[r] += p;
                }
                *(float4*)&pbuf[wave][rb][lane][0] = pv;
            }
        }
        __syncthreads();
        for (int j = 0; j < 64; j++) {
            float hv = hwc[j][lane];
#pragma unroll
            for (int rb = 0; rb < 8; rb++) {
                float4 p4 = *(const float4*)&pbuf[wave][rb][j][0];
                acc[rb * 4 + 0] += p4.x * hv;
                acc[rb * 4 + 1] += p4.y * hv;
                acc[rb * 4 + 2] += p4.z * hv;
                acc[rb * 4 + 3] += p4.w * hv;
            }
        }
        __syncthreads();
    }
#pragma unroll
    for (int r = 0; r < 32; r++) {
        float dsum = den[r];
#pragma unroll
        for (int off = 32; off > 0; off >>= 1) dsum += __shfl_down(dsum, off, 64);
        dsum = __shfl(dsum, 0, 64);
        hnew[(size_t)(b * D_ + rowbase + r) * HID_ + h * OUT_ + lane] = acc[r] / dsum;
    }
}

// ---------------------------------------------------------------------------
// 6) h = LayerNorm(h + hnew)*g + b; writes fp32 h and bf16 h copy
// ---------------------------------------------------------------------------
__global__ __launch_bounds__(256) void addln_k(float* __restrict__ h,
                                               const float* __restrict__ hn,
                                               const float* __restrict__ g,
                                               const float* __restrict__ bb,
                                               unsigned short* __restrict__ hbf) {
    int row = blockIdx.x;
    int c = threadIdx.x;
    float v = h[(size_t)row * HID_ + c] + hn[(size_t)row * HID_ + c];
    __shared__ float red[256];
    red[c] = v;
    __syncthreads();
    for (int s = 128; s > 0; s >>= 1) {
        if (c < s) red[c] += red[c + s];
        __syncthreads();
    }
    float mu = red[0] * (1.f / HID_);
    __syncthreads();
    float d = v - mu;
    red[c] = d * d;
    __syncthreads();
    for (int s = 128; s > 0; s >>= 1) {
        if (c < s) red[c] += red[c + s];
        __syncthreads();
    }
    float var = red[0] * (1.f / HID_);
    float res = d * rsqrtf(var + EPS_) * g[c] + bb[c];
    h[(size_t)row * HID_ + c]   = res;
    hbf[(size_t)row * HID_ + c] = f2bf(res);
}

// ---------------------------------------------------------------------------
extern "C" void kernel_launch(void* const* d_in, const int* in_sizes, int n_in,
                              void* d_out, int out_size, void* d_ws, size_t ws_size,
                              hipStream_t stream) {
    const float* X_obs = (const float*)d_in[0];
    const float* mask  = (const float*)d_in[1];
    const float* W_in  = (const float*)d_in[2];
    const float* b_in  = (const float*)d_in[3];
    const float* gat_W = (const float*)d_in[4];
    const float* gat_a = (const float*)d_in[5];
    const float* ln_g  = (const float*)d_in[6];
    const float* ln_b  = (const float*)d_in[7];
    const float* W_out = (const float*)d_in[8];
    const float* b_out = (const float*)d_in[9];
    float* out = (float*)d_out;

    // Workspace layout (29.3 MB; previous round used 34.3 MB OK):
    //  [0,16M):  A_in bf16 (M x 1024); after concat GEMM reused as:
    //            hwb fp32 (M x 256, 8 MB) at 0 and hnew fp32 (8 MB) at 8M
    //  [16,24M): hbuf fp32 (M x 256)
    //  [24,28M): hbf bf16 (M x 256)
    //  [28M...): Wt_in bf16 (0.5M), Wcat_t bf16 (0.25M), Wt_out bf16 (0.25M),
    //            slb/srb/rmx fp32
    char* base = (char*)d_ws;
    unsigned short* Ain  = (unsigned short*)base;
    float* hwb  = (float*)base;
    float* hnew = (float*)(base + (8u << 20));
    float* hbuf = (float*)(base + (16u << 20));
    unsigned short* hbf   = (unsigned short*)(base + (24u << 20));
    unsigned short* Wt_in = (unsigned short*)(base + (28u << 20));
    unsigned short* Wcat  = Wt_in + (size_t)HID_ * KIN_;        // 256*1024
    unsigned short* WtO   = Wcat + (size_t)NL_ * HID_ * HID_;   // 2*256*256
    float* slb = (float*)(WtO + (size_t)T_ * HID_);             // 512*256
    float* srb = slb + B_ * NH_ * D_;
    float* rmx = srb + B_ * NH_ * D_;

    impute_k<<<DT_ / 256, 256, 0, stream>>>(X_obs, mask, Ain);
    tconv_k<<<(KIN_ * HID_) / 256, 256, 0, stream>>>(W_in, Wt_in, KIN_, HID_);
    wcat_t_k<<<(NL_ * HID_ * HID_) / 256, 256, 0, stream>>>(gat_W, Wcat);
    tconv_k<<<(HID_ * T_) / 256, 256, 0, stream>>>(W_out, WtO, HID_, T_);

    // h = [X_mean|mask] @ W_in + b_in   (8192x1024)@(1024x256), fp32+bf16 out
    gemm_bf16_k<true><<<dim3(HID_ / 64, M_ / 128), 256, 0, stream>>>(
        Ain, Wt_in, b_in, hbuf, hbf, M_, HID_, KIN_);

    for (int l = 0; l < NL_; l++) {
        gemm_bf16_k<false><<<dim3(HID_ / 64, M_ / 128), 256, 0, stream>>>(
            hbf, Wcat + (size_t)l * HID_ * HID_, nullptr, hwb, nullptr, M_, HID_, HID_);
        slr_k<<<B_ * NH_, 256, 0, stream>>>(hwb, gat_a, l, slb, srb, rmx);
        attn_k<<<dim3(B_ * NH_, D_ / 128), 256, 0, stream>>>(hwb, slb, srb, rmx, hnew);
        addln_k<<<M_, 256, 0, stream>>>(hbuf, hnew, ln_g + (size_t)l * HID_,
                                        ln_b + (size_t)l * HID_, hbf);
    }

    // out = h @ W_out + b_out  (8192x256)@(256x512), fp32 out
    gemm_bf16_k<false><<<dim3(T_ / 64, M_ / 128), 256, 0, stream>>>(
        hbf, WtO, b_out, out, nullptr, M_, T_, HID_);
}

// Round 4
// 237.967 us; speedup vs baseline: 2.4568x; 1.7614x over previous
//
#include <hip/hip_runtime.h>
#include <hip/hip_bf16.h>

// Problem constants
constexpr int B_   = 8;
constexpr int D_   = 1024;
constexpr int T_   = 512;
constexpr int HID_ = 256;
constexpr int NH_  = 4;
constexpr int NL_  = 2;
constexpr int OUT_ = 64;
constexpr float ALPHA_ = 0.2f;
constexpr float EPS_   = 1e-5f;
constexpr int M_ = B_ * D_;      // 8192 rows
constexpr int DT_ = D_ * T_;     // 524288
constexpr int KIN_ = 2 * T_;     // 1024

typedef __attribute__((ext_vector_type(8))) short short8;   // 8 bf16 (4 VGPRs)
typedef __attribute__((ext_vector_type(4))) float floatx4;  // 4 fp32 acc

__device__ __forceinline__ unsigned short f2bf(float f) {
    unsigned int u = __float_as_uint(f);
    unsigned int r = u + 0x7fffu + ((u >> 16) & 1u);   // round-to-nearest-even
    return (unsigned short)(r >> 16);
}
__device__ __forceinline__ float bf2f(unsigned short u) {
    return __uint_as_float((unsigned int)u << 16);
}

// ---------------------------------------------------------------------------
// 1) Imputation -> packed bf16 concat matrix A_in[M][1024] = [X_mean | mask]
// ---------------------------------------------------------------------------
__global__ __launch_bounds__(256) void impute_k(const float* __restrict__ X,
                                                const float* __restrict__ Mk,
                                                unsigned short* __restrict__ Ain) {
    int idx = blockIdx.x * 256 + threadIdx.x;   // over D*T
    int t = idx & (T_ - 1);
    int d = idx >> 9;                            // T_=512
    float x[B_], m[B_];
    float s = 0.f, c = 0.f;
#pragma unroll
    for (int b = 0; b < B_; b++) {
        x[b] = X[(size_t)b * DT_ + idx];
        m[b] = Mk[(size_t)b * DT_ + idx];
        s += x[b] * m[b];
        c += m[b];
    }
    float pm = s / (c + 1e-10f);
#pragma unroll
    for (int b = 0; b < B_; b++) {
        float xm = x[b] * m[b] + (1.f - m[b]) * pm;
        size_t row = (size_t)b * D_ + d;
        Ain[row * KIN_ + t]      = f2bf(xm);
        Ain[row * KIN_ + T_ + t] = f2bf(m[b]);
    }
}

// ---------------------------------------------------------------------------
// 2a) Generic transpose+convert: src fp32 [K][N] -> dst bf16 [N][K]
// ---------------------------------------------------------------------------
__global__ __launch_bounds__(256) void tconv_k(const float* __restrict__ src,
                                               unsigned short* __restrict__ dst,
                                               int K, int N) {
    int idx = blockIdx.x * 256 + threadIdx.x;
    if (idx >= K * N) return;
    int n = idx / K, k = idx - n * K;
    dst[idx] = f2bf(src[(size_t)k * N + n]);
}

// 2b) gat_W (NL,NH,HID,OUT) -> Wcat_t[l][n=NH*OUT][k=HID] bf16 (transposed)
__global__ __launch_bounds__(256) void wcat_t_k(const float* __restrict__ gatW,
                                                unsigned short* __restrict__ Wt) {
    int idx = blockIdx.x * 256 + threadIdx.x;   // over NL*256*256 = 131072
    int l = idx >> 16;
    int n = (idx >> 8) & 255;
    int k = idx & 255;
    int h = n >> 6, e = n & 63;
    Wt[idx] = f2bf(gatW[(((size_t)(l * NH_ + h) * HID_) + k) * OUT_ + e]);
}

// ---------------------------------------------------------------------------
// 3) bf16 MFMA GEMM: C = A[M,K] @ Bt[N,K]^T. BM=128 BN=64 BK=32, 4 waves.
//    MODE 0: fp32 C (+bias). MODE 1: fp32 C + bf16 copy (+bias).
//    MODE 2: per-head transposed bf16 only -> hwT[bh][e][m]  (Nsz must be 256)
// ---------------------------------------------------------------------------
template <int MODE>
__global__ __launch_bounds__(256) void gemm_bf16_k(
        const unsigned short* __restrict__ A,    // M x K bf16
        const unsigned short* __restrict__ Bt,   // N x K bf16 (B transposed)
        const float* __restrict__ bias,          // N or null
        float* __restrict__ C,                   // M x N fp32 (MODE 0/1)
        unsigned short* __restrict__ Cb,         // bf16 copy (MODE1) / hwT (MODE2)
        int Msz, int Nsz, int Ksz) {
    __shared__ __align__(16) unsigned short As[128 * 32];  // [row][k] 8 KB
    __shared__ __align__(16) unsigned short Bs[64 * 32];   // [col][k] 4 KB
    int tid = threadIdx.x;
    int wave = tid >> 6, lane = tid & 63;
    int q = lane >> 4, r16 = lane & 15;
    int rowbase = blockIdx.y * 128;
    int colbase = blockIdx.x * 64;

    floatx4 acc[2][4];
#pragma unroll
    for (int i = 0; i < 2; i++)
#pragma unroll
        for (int j = 0; j < 4; j++) acc[i][j] = (floatx4)0.f;

    for (int kt = 0; kt < Ksz; kt += 32) {
#pragma unroll
        for (int i = 0; i < 2; i++) {
            int c = tid + i * 256;
            int row = c >> 2, off = (c & 3) * 8;
            *(uint4*)&As[c * 8] =
                *(const uint4*)&A[(size_t)(rowbase + row) * Ksz + kt + off];
        }
        {
            int n = tid >> 2, off = (tid & 3) * 8;
            *(uint4*)&Bs[tid * 8] =
                *(const uint4*)&Bt[(size_t)(colbase + n) * Ksz + kt + off];
        }
        __syncthreads();
        short8 a[2], b[4];
#pragma unroll
        for (int mi = 0; mi < 2; mi++)
            a[mi] = *(const short8*)&As[(wave * 32 + mi * 16 + r16) * 32 + q * 8];
#pragma unroll
        for (int ni = 0; ni < 4; ni++)
            b[ni] = *(const short8*)&Bs[(ni * 16 + r16) * 32 + q * 8];
#pragma unroll
        for (int mi = 0; mi < 2; mi++)
#pragma unroll
            for (int ni = 0; ni < 4; ni++)
                acc[mi][ni] = __builtin_amdgcn_mfma_f32_16x16x32_bf16(
                    a[mi], b[ni], acc[mi][ni], 0, 0, 0);
        __syncthreads();
    }
    // epilogue. C/D map: col=lane&15, row=(lane>>4)*4+reg
    if constexpr (MODE == 2) {
        // hwT[bh][e][m], bh = b*4 + h; h == blockIdx.x since Nsz==256
        int bhh = ((rowbase >> 10) << 2) + blockIdx.x;
        int mbase = (rowbase & (D_ - 1)) + wave * 32;
#pragma unroll
        for (int mi = 0; mi < 2; mi++) {
#pragma unroll
            for (int ni = 0; ni < 4; ni++) {
                int e = ni * 16 + r16;
                ushort4 pk;
                pk.x = f2bf(acc[mi][ni][0]);
                pk.y = f2bf(acc[mi][ni][1]);
                pk.z = f2bf(acc[mi][ni][2]);
                pk.w = f2bf(acc[mi][ni][3]);
                int mloc = mbase + mi * 16 + q * 4;
                *(ushort4*)&Cb[((size_t)(bhh * 64 + e) << 10) + mloc] = pk;
            }
        }
    } else {
#pragma unroll
        for (int mi = 0; mi < 2; mi++) {
#pragma unroll
            for (int rr = 0; rr < 4; rr++) {
                int row = rowbase + wave * 32 + mi * 16 + q * 4 + rr;
#pragma unroll
                for (int ni = 0; ni < 4; ni++) {
                    int col = colbase + ni * 16 + r16;
                    float v = acc[mi][ni][rr] + (bias ? bias[col] : 0.f);
                    C[(size_t)row * Nsz + col] = v;
                    if constexpr (MODE == 1) Cb[(size_t)row * Nsz + col] = f2bf(v);
                }
            }
        }
    }
}

// ---------------------------------------------------------------------------
// 4) s_l, s_r from hwT bf16, + per-chunk max(s_r). grid (32 bh, 4 chunks).
// ---------------------------------------------------------------------------
__global__ __launch_bounds__(256) void slr_k(const unsigned short* __restrict__ hwT,
                                             const float* __restrict__ gat_a,
                                             int l,
                                             float* __restrict__ s_l,
                                             float* __restrict__ s_r,
                                             float* __restrict__ rmax4) {
    int bh = blockIdx.x;
    int h = bh & 3;
    int n = blockIdx.y * 256 + threadIdx.x;
    __shared__ float al[OUT_], ar[OUT_];
    __shared__ float red[256];
    if (threadIdx.x < OUT_)
        al[threadIdx.x] = gat_a[(size_t)(l * NH_ + h) * 2 * OUT_ + threadIdx.x];
    else if (threadIdx.x < 2 * OUT_)
        ar[threadIdx.x - OUT_] = gat_a[(size_t)(l * NH_ + h) * 2 * OUT_ + threadIdx.x];
    __syncthreads();
    const unsigned short* base = hwT + ((size_t)(bh * 64) << 10) + n;
    float sl = 0.f, sr = 0.f;
#pragma unroll 8
    for (int e = 0; e < OUT_; e++) {
        float v = bf2f(base[(size_t)e << 10]);
        sl += v * al[e];
        sr += v * ar[e];
    }
    s_l[bh * D_ + n] = sl;
    s_r[bh * D_ + n] = sr;
    red[threadIdx.x] = sr;
    __syncthreads();
    for (int s = 128; s > 0; s >>= 1) {
        if (threadIdx.x < s) red[threadIdx.x] = fmaxf(red[threadIdx.x], red[threadIdx.x + s]);
        __syncthreads();
    }
    if (threadIdx.x == 0) rmax4[bh * 4 + blockIdx.y] = red[0];
}

// ---------------------------------------------------------------------------
// 5) Attention via MFMA. grid (32 bh, 16 rowblocks of 64). 256 thr, 4 waves.
//    Wave = one 16-row tile. P fragments (bf16) computed in registers;
//    V chunks staged in LDS [64][136] (pad 8 -> b128 bank floor).
// ---------------------------------------------------------------------------
__global__ __launch_bounds__(256) void attn_k(const unsigned short* __restrict__ hwT,
                                              const float* __restrict__ sl_g,
                                              const float* __restrict__ sr_g,
                                              const float* __restrict__ rmax4,
                                              float* __restrict__ hnew) {
    int bh = blockIdx.x;
    int b = bh >> 2, h = bh & 3;
    int tid = threadIdx.x;
    int wave = tid >> 6, lane = tid & 63;
    int q = lane >> 4, r16 = lane & 15;

    __shared__ float srs[D_];                              // 4 KB
    __shared__ __align__(16) unsigned short Vt[64][136];   // 17 KB, +8 pad
    __shared__ float den_lds[64];

    // stage s_r (1024 floats, one float4/thread)
    *(float4*)&srs[tid * 4] = *(const float4*)&sr_g[bh * D_ + tid * 4];

    float rm = fmaxf(fmaxf(rmax4[bh * 4 + 0], rmax4[bh * 4 + 1]),
                     fmaxf(rmax4[bh * 4 + 2], rmax4[bh * 4 + 3]));
    int row0 = blockIdx.y * 64 + wave * 16;       // block covers 64 rows
    float sl = sl_g[bh * D_ + row0 + r16];        // a-frag row = r16
    float xm = sl + rm;
    float Mn = fmaxf(xm, ALPHA_ * xm);            // exact row max of e

    floatx4 acc[4];
#pragma unroll
    for (int i = 0; i < 4; i++) acc[i] = (floatx4)0.f;
    float dsum = 0.f;

    const unsigned short* vbase = hwT + ((size_t)(bh * 64) << 10);

    for (int mc = 0; mc < D_; mc += 128) {
        __syncthreads();   // first iter: covers srs; later: protect Vt overwrite
        // stage Vt[64][128]: 1024 slots of 8 ushort, 4 per thread
#pragma unroll
        for (int i = 0; i < 4; i++) {
            int s = tid + i * 256;
            int e = s >> 4, part = s & 15;
            *(uint4*)&Vt[e][part * 8] = *(const uint4*)&vbase[((size_t)e << 10) + mc + part * 8];
        }
        __syncthreads();
#pragma unroll
        for (int kk = 0; kk < 128; kk += 32) {
            int m0 = mc + kk + q * 8;             // a-frag k = q*8 + j
            float4 s0 = *(const float4*)&srs[m0];
            float4 s1 = *(const float4*)&srs[m0 + 4];
            float sr8[8] = {s0.x, s0.y, s0.z, s0.w, s1.x, s1.y, s1.z, s1.w};
            float p[8];
#pragma unroll
            for (int j = 0; j < 8; j++) {
                float x = sl + sr8[j];
                float e = fmaxf(x, ALPHA_ * x);   // leaky_relu, alpha<1
                float pj = __expf(e - Mn);
                dsum += pj;
                p[j] = pj;
            }
            union { unsigned int u[4]; short8 s8; } cv;
#pragma unroll
            for (int j = 0; j < 4; j++) {
                unsigned int lo = (__float_as_uint(p[2 * j]) + 0x8000u) >> 16;
                unsigned int hi = (__float_as_uint(p[2 * j + 1]) + 0x8000u) & 0xffff0000u;
                cv.u[j] = hi | lo;
            }
#pragma unroll
            for (int ni = 0; ni < 4; ni++) {
                short8 bfr = *(const short8*)&Vt[ni * 16 + r16][kk + q * 8];
                acc[ni] = __builtin_amdgcn_mfma_f32_16x16x32_bf16(cv.s8, bfr, acc[ni], 0, 0, 0);
            }
        }
    }
    // den: lane has row r16's partial over its q-slice; reduce over q
    dsum += __shfl_xor(dsum, 16);
    dsum += __shfl_xor(dsum, 32);
    if (q == 0) den_lds[wave * 16 + r16] = dsum;
    __syncthreads();
    // C layout: row = q*4+rr, col = ni*16+r16
#pragma unroll
    for (int rr = 0; rr < 4; rr++) {
        int rloc = q * 4 + rr;
        float rden = 1.f / den_lds[wave * 16 + rloc];
        size_t grow = (size_t)(b * D_ + blockIdx.y * 64 + wave * 16 + rloc);
#pragma unroll
        for (int ni = 0; ni < 4; ni++) {
            hnew[grow * HID_ + h * OUT_ + ni * 16 + r16] = acc[ni][rr] * rden;
        }
    }
}

// ---------------------------------------------------------------------------
// 6) h = LayerNorm(h + hnew)*g + b; writes fp32 h and bf16 h copy
// ---------------------------------------------------------------------------
__global__ __launch_bounds__(256) void addln_k(float* __restrict__ h,
                                               const float* __restrict__ hn,
                                               const float* __restrict__ g,
                                               const float* __restrict__ bb,
                                               unsigned short* __restrict__ hbf) {
    int row = blockIdx.x;
    int c = threadIdx.x;
    float v = h[(size_t)row * HID_ + c] + hn[(size_t)row * HID_ + c];
    __shared__ float red[256];
    red[c] = v;
    __syncthreads();
    for (int s = 128; s > 0; s >>= 1) {
        if (c < s) red[c] += red[c + s];
        __syncthreads();
    }
    float mu = red[0] * (1.f / HID_);
    __syncthreads();
    float d = v - mu;
    red[c] = d * d;
    __syncthreads();
    for (int s = 128; s > 0; s >>= 1) {
        if (c < s) red[c] += red[c + s];
        __syncthreads();
    }
    float var = red[0] * (1.f / HID_);
    float res = d * rsqrtf(var + EPS_) * g[c] + bb[c];
    h[(size_t)row * HID_ + c]   = res;
    hbf[(size_t)row * HID_ + c] = f2bf(res);
}

// ---------------------------------------------------------------------------
extern "C" void kernel_launch(void* const* d_in, const int* in_sizes, int n_in,
                              void* d_out, int out_size, void* d_ws, size_t ws_size,
                              hipStream_t stream) {
    const float* X_obs = (const float*)d_in[0];
    const float* mask  = (const float*)d_in[1];
    const float* W_in  = (const float*)d_in[2];
    const float* b_in  = (const float*)d_in[3];
    const float* gat_W = (const float*)d_in[4];
    const float* gat_a = (const float*)d_in[5];
    const float* ln_g  = (const float*)d_in[6];
    const float* ln_b  = (const float*)d_in[7];
    const float* W_out = (const float*)d_in[8];
    const float* b_out = (const float*)d_in[9];
    float* out = (float*)d_out;

    // Workspace (~29.3 MB):
    //  [0,16M):  Ain bf16 (M x 1024); dead after concat GEMM, then reused:
    //            hwT bf16 [32 bh][64 e][1024 m] (4 MB) at 0,
    //            hnew fp32 (8 MB) at 4M..12M
    //  [16,24M): hbuf fp32 (M x 256)
    //  [24,28M): hbf bf16 (M x 256)
    //  [28M...): Wt_in, Wcat, WtO (bf16), slb/srb/rmx (fp32)
    char* base = (char*)d_ws;
    unsigned short* Ain  = (unsigned short*)base;
    unsigned short* hwT  = (unsigned short*)base;
    float* hnew = (float*)(base + (4u << 20));
    float* hbuf = (float*)(base + (16u << 20));
    unsigned short* hbf   = (unsigned short*)(base + (24u << 20));
    unsigned short* Wt_in = (unsigned short*)(base + (28u << 20));
    unsigned short* Wcat  = Wt_in + (size_t)HID_ * KIN_;        // 256*1024
    unsigned short* WtO   = Wcat + (size_t)NL_ * HID_ * HID_;   // 2*256*256
    float* slb = (float*)(WtO + (size_t)T_ * HID_);             // 512*256
    float* srb = slb + B_ * NH_ * D_;
    float* rmx = srb + B_ * NH_ * D_;

    impute_k<<<DT_ / 256, 256, 0, stream>>>(X_obs, mask, Ain);
    tconv_k<<<(KIN_ * HID_) / 256, 256, 0, stream>>>(W_in, Wt_in, KIN_, HID_);
    wcat_t_k<<<(NL_ * HID_ * HID_) / 256, 256, 0, stream>>>(gat_W, Wcat);
    tconv_k<<<(HID_ * T_) / 256, 256, 0, stream>>>(W_out, WtO, HID_, T_);

    // h = [X_mean|mask] @ W_in + b_in   (8192x1024)@(1024x256), fp32+bf16 out
    gemm_bf16_k<1><<<dim3(HID_ / 64, M_ / 128), 256, 0, stream>>>(
        Ain, Wt_in, b_in, hbuf, hbf, M_, HID_, KIN_);

    for (int l = 0; l < NL_; l++) {
        // hW = h @ Wcat[l] -> per-head transposed bf16 hwT
        gemm_bf16_k<2><<<dim3(HID_ / 64, M_ / 128), 256, 0, stream>>>(
            hbf, Wcat + (size_t)l * HID_ * HID_, nullptr, nullptr, hwT, M_, HID_, HID_);
        slr_k<<<dim3(B_ * NH_, 4), 256, 0, stream>>>(hwT, gat_a, l, slb, srb, rmx);
        attn_k<<<dim3(B_ * NH_, D_ / 64), 256, 0, stream>>>(hwT, slb, srb, rmx, hnew);
        addln_k<<<M_, 256, 0, stream>>>(hbuf, hnew, ln_g + (size_t)l * HID_,
                                        ln_b + (size_t)l * HID_, hbf);
    }

    // out = h @ W_out + b_out  (8192x256)@(256x512), fp32 out
    gemm_bf16_k<0><<<dim3(T_ / 64, M_ / 128), 256, 0, stream>>>(
        hbf, WtO, b_out, out, nullptr, M_, T_, HID_);
}

// Round 5
// 223.283 us; speedup vs baseline: 2.6184x; 1.0658x over previous
//
#include <hip/hip_runtime.h>
#include <hip/hip_bf16.h>

// Problem constants
constexpr int B_   = 8;
constexpr int D_   = 1024;
constexpr int T_   = 512;
constexpr int HID_ = 256;
constexpr int NH_  = 4;
constexpr int NL_  = 2;
constexpr int OUT_ = 64;
constexpr float ALPHA_ = 0.2f;
constexpr float EPS_   = 1e-5f;
constexpr int M_ = B_ * D_;      // 8192 rows
constexpr int DT_ = D_ * T_;     // 524288
constexpr int KIN_ = 2 * T_;     // 1024

typedef __attribute__((ext_vector_type(8))) short short8;   // 8 bf16 (4 VGPRs)
typedef __attribute__((ext_vector_type(4))) float floatx4;  // 4 fp32 acc

__device__ __forceinline__ unsigned short f2bf(float f) {
    unsigned int u = __float_as_uint(f);
    unsigned int r = u + 0x7fffu + ((u >> 16) & 1u);   // round-to-nearest-even
    return (unsigned short)(r >> 16);
}
__device__ __forceinline__ float bf2f(unsigned short u) {
    return __uint_as_float((unsigned int)u << 16);
}
// monotone float<->uint key for atomicMax on signed floats
__device__ __forceinline__ unsigned int kenc(float f) {
    unsigned int u = __float_as_uint(f);
    return (u & 0x80000000u) ? ~u : (u | 0x80000000u);
}
__device__ __forceinline__ float kdec(unsigned int k) {
    unsigned int u = (k & 0x80000000u) ? (k ^ 0x80000000u) : ~k;
    return __uint_as_float(u);
}

// ---------------------------------------------------------------------------
// 1) Imputation -> packed bf16 concat matrix A_in[M][1024] = [X_mean | mask]
//    float4-vectorized: thread handles 4 consecutive t. grid 512 blocks.
// ---------------------------------------------------------------------------
__global__ __launch_bounds__(256) void impute_k(const float* __restrict__ X,
                                                const float* __restrict__ Mk,
                                                unsigned short* __restrict__ Ain) {
    int idx4 = (blockIdx.x * 256 + threadIdx.x) * 4;   // over D*T
    int t = idx4 & (T_ - 1);
    int d = idx4 >> 9;
    float4 x[B_], m[B_];
    float4 s = {0, 0, 0, 0}, c = {0, 0, 0, 0};
#pragma unroll
    for (int b = 0; b < B_; b++) {
        x[b] = *(const float4*)&X[(size_t)b * DT_ + idx4];
        m[b] = *(const float4*)&Mk[(size_t)b * DT_ + idx4];
        s.x += x[b].x * m[b].x; s.y += x[b].y * m[b].y;
        s.z += x[b].z * m[b].z; s.w += x[b].w * m[b].w;
        c.x += m[b].x; c.y += m[b].y; c.z += m[b].z; c.w += m[b].w;
    }
    float4 pm;
    pm.x = s.x / (c.x + 1e-10f); pm.y = s.y / (c.y + 1e-10f);
    pm.z = s.z / (c.z + 1e-10f); pm.w = s.w / (c.w + 1e-10f);
#pragma unroll
    for (int b = 0; b < B_; b++) {
        size_t row = (size_t)b * D_ + d;
        ushort4 xm, mk;
        xm.x = f2bf(x[b].x * m[b].x + (1.f - m[b].x) * pm.x);
        xm.y = f2bf(x[b].y * m[b].y + (1.f - m[b].y) * pm.y);
        xm.z = f2bf(x[b].z * m[b].z + (1.f - m[b].z) * pm.z);
        xm.w = f2bf(x[b].w * m[b].w + (1.f - m[b].w) * pm.w);
        mk.x = f2bf(m[b].x); mk.y = f2bf(m[b].y);
        mk.z = f2bf(m[b].z); mk.w = f2bf(m[b].w);
        *(ushort4*)&Ain[row * KIN_ + t]      = xm;
        *(ushort4*)&Ain[row * KIN_ + T_ + t] = mk;
    }
}

// ---------------------------------------------------------------------------
// 2) Fused weight prep: Wt_in (bf16 [256][1024]), Wcat (bf16 [l][256][256]),
//    WtO (bf16 [512][256]), rmaxkey init. 2048 blocks x 256.
// ---------------------------------------------------------------------------
__global__ __launch_bounds__(256) void wprep_k(const float* __restrict__ W_in,
                                               const float* __restrict__ gatW,
                                               const float* __restrict__ W_out,
                                               unsigned short* __restrict__ Wt_in,
                                               unsigned short* __restrict__ Wcat,
                                               unsigned short* __restrict__ WtO,
                                               unsigned int* __restrict__ rmaxkey) {
    int idx = blockIdx.x * 256 + threadIdx.x;
    if (idx < 64) rmaxkey[idx] = 0u;           // per (l,bh) max-key init
    if (idx < 262144) {
        int n = idx >> 10, k = idx & 1023;     // Wt_in[n][k] = W_in[k][n]
        Wt_in[idx] = f2bf(W_in[(size_t)k * HID_ + n]);
    } else if (idx < 393216) {
        int j = idx - 262144;
        int l = j >> 16, n = (j >> 8) & 255, k = j & 255;
        int h = n >> 6, e = n & 63;
        Wcat[j] = f2bf(gatW[(((size_t)(l * NH_ + h) * HID_) + k) * OUT_ + e]);
    } else {
        int j = idx - 393216;
        int n = j >> 8, k = j & 255;           // WtO[n][k] = W_out[k][n]
        WtO[j] = f2bf(W_out[(size_t)k * T_ + n]);
    }
}

// ---------------------------------------------------------------------------
// 3) bf16 MFMA GEMM, ping-pong LDS double-buffer, 1 barrier/iter.
//    C = A[M,K] @ Bt[N,K]^T. BM=128 BN=64 BK=32, 4 waves.
//    MODE 0: fp32 C (+bias). MODE 1: fp32 C + bf16 copy (+bias).
//    MODE 2: per-head transposed bf16 -> hwT[bh][e][m], fused s_l/s_r/rmax.
// ---------------------------------------------------------------------------
template <int MODE>
__global__ __launch_bounds__(256) void gemm_bf16_k(
        const unsigned short* __restrict__ A,    // M x K bf16
        const unsigned short* __restrict__ Bt,   // N x K bf16 (B transposed)
        const float* __restrict__ bias,          // N or null (MODE 0/1)
        float* __restrict__ C,                   // M x N fp32 (MODE 0/1)
        unsigned short* __restrict__ Cb,         // bf16 copy (MODE1) / hwT (MODE2)
        const float* __restrict__ ga,            // gat_a + l*512 (MODE2)
        float* __restrict__ s_l,                 // (MODE2)
        float* __restrict__ s_r,                 // (MODE2)
        unsigned int* __restrict__ rmaxkey,      // + l*32 (MODE2)
        int Nsz, int Ksz) {
    __shared__ __align__(16) unsigned short As[2][128 * 32];  // 16 KB
    __shared__ __align__(16) unsigned short Bs[2][64 * 32];   // 8 KB
    int tid = threadIdx.x;
    int wave = tid >> 6, lane = tid & 63;
    int q = lane >> 4, r16 = lane & 15;
    int rowbase = blockIdx.y * 128;
    int colbase = blockIdx.x * 64;

    // staging addresses
    int arow0 = tid >> 2,        aoff0 = (tid & 3) * 8;          // slots 0..255
    int arow1 = (tid + 256) >> 2, aoff1 = (tid & 3) * 8;         // slots 256..511
    int brow = tid >> 2, boff = (tid & 3) * 8;
    const unsigned short* Ap0 = A + (size_t)(rowbase + arow0) * Ksz + aoff0;
    const unsigned short* Ap1 = A + (size_t)(rowbase + arow1) * Ksz + aoff1;
    const unsigned short* Bp  = Bt + (size_t)(colbase + brow) * Ksz + boff;

    floatx4 acc[2][4];
#pragma unroll
    for (int i = 0; i < 2; i++)
#pragma unroll
        for (int j = 0; j < 4; j++) acc[i][j] = (floatx4)0.f;

    uint4 ar0 = *(const uint4*)Ap0;
    uint4 ar1 = *(const uint4*)Ap1;
    uint4 br  = *(const uint4*)Bp;
    *(uint4*)&As[0][tid * 8]         = ar0;
    *(uint4*)&As[0][(tid + 256) * 8] = ar1;
    *(uint4*)&Bs[0][tid * 8]         = br;

    int nk = Ksz >> 5;
    for (int it = 0; it < nk; it++) {
        int cur = it & 1;
        __syncthreads();
        if (it + 1 < nk) {
            int kt2 = (it + 1) << 5;
            ar0 = *(const uint4*)(Ap0 + kt2);
            ar1 = *(const uint4*)(Ap1 + kt2);
            br  = *(const uint4*)(Bp + kt2);
        }
        short8 a[2], b[4];
#pragma unroll
        for (int mi = 0; mi < 2; mi++)
            a[mi] = *(const short8*)&As[cur][(wave * 32 + mi * 16 + r16) * 32 + q * 8];
#pragma unroll
        for (int ni = 0; ni < 4; ni++)
            b[ni] = *(const short8*)&Bs[cur][(ni * 16 + r16) * 32 + q * 8];
#pragma unroll
        for (int mi = 0; mi < 2; mi++)
#pragma unroll
            for (int ni = 0; ni < 4; ni++)
                acc[mi][ni] = __builtin_amdgcn_mfma_f32_16x16x32_bf16(
                    a[mi], b[ni], acc[mi][ni], 0, 0, 0);
        if (it + 1 < nk) {
            int nxt = cur ^ 1;
            *(uint4*)&As[nxt][tid * 8]         = ar0;
            *(uint4*)&As[nxt][(tid + 256) * 8] = ar1;
            *(uint4*)&Bs[nxt][tid * 8]         = br;
        }
    }
    // ---- epilogue. C/D map: col=lane&15, row=(lane>>4)*4+reg ----
    if constexpr (MODE == 2) {
        int bhh = ((rowbase >> 10) << 2) + blockIdx.x;   // b*4 + h
        int nbase = (rowbase & (D_ - 1)) + wave * 32;
        // hwT[bh][e][m] bf16
#pragma unroll
        for (int mi = 0; mi < 2; mi++) {
#pragma unroll
            for (int ni = 0; ni < 4; ni++) {
                int e = ni * 16 + r16;
                ushort4 pk;
                pk.x = f2bf(acc[mi][ni][0]);
                pk.y = f2bf(acc[mi][ni][1]);
                pk.z = f2bf(acc[mi][ni][2]);
                pk.w = f2bf(acc[mi][ni][3]);
                *(ushort4*)&Cb[((size_t)(bhh * 64 + e) << 10) + nbase + mi * 16 + q * 4] = pk;
            }
        }
        // fused s_l / s_r from fp32 acc: reduce over e (ni regs + r16 lanes)
        const float* gab = ga + blockIdx.x * 2 * OUT_;
        float al4[4], ar4[4];
#pragma unroll
        for (int ni = 0; ni < 4; ni++) {
            al4[ni] = gab[ni * 16 + r16];
            ar4[ni] = gab[OUT_ + ni * 16 + r16];
        }
        float slv[2][4], srv[2][4];
#pragma unroll
        for (int mi = 0; mi < 2; mi++)
#pragma unroll
            for (int rr = 0; rr < 4; rr++) {
                float s1 = 0.f, s2 = 0.f;
#pragma unroll
                for (int ni = 0; ni < 4; ni++) {
                    s1 += acc[mi][ni][rr] * al4[ni];
                    s2 += acc[mi][ni][rr] * ar4[ni];
                }
                slv[mi][rr] = s1;
                srv[mi][rr] = s2;
            }
#pragma unroll
        for (int off = 1; off < 16; off <<= 1) {
#pragma unroll
            for (int mi = 0; mi < 2; mi++)
#pragma unroll
                for (int rr = 0; rr < 4; rr++) {
                    slv[mi][rr] += __shfl_xor(slv[mi][rr], off, 64);
                    srv[mi][rr] += __shfl_xor(srv[mi][rr], off, 64);
                }
        }
        // writers: r16 0..7 -> s_l slots, 8..15 -> s_r slots
        {
            int slot = r16 & 7;
            int mi = slot >> 2, rr = slot & 3;
            int n = nbase + mi * 16 + q * 4 + rr;
            if (r16 < 8) s_l[bhh * D_ + n] = slv[mi][rr];
            else         s_r[bhh * D_ + n] = srv[mi][rr];
        }
        // per-(l,bh) running max of s_r
        float mx = -1e30f;
#pragma unroll
        for (int mi = 0; mi < 2; mi++)
#pragma unroll
            for (int rr = 0; rr < 4; rr++) mx = fmaxf(mx, srv[mi][rr]);
        if (lane == 0) atomicMax(&rmaxkey[bhh], kenc(mx));
    } else {
#pragma unroll
        for (int mi = 0; mi < 2; mi++) {
#pragma unroll
            for (int rr = 0; rr < 4; rr++) {
                int row = rowbase + wave * 32 + mi * 16 + q * 4 + rr;
#pragma unroll
                for (int ni = 0; ni < 4; ni++) {
                    int col = colbase + ni * 16 + r16;
                    float v = acc[mi][ni][rr] + (bias ? bias[col] : 0.f);
                    C[(size_t)row * Nsz + col] = v;
                    if constexpr (MODE == 1) Cb[(size_t)row * Nsz + col] = f2bf(v);
                }
            }
        }
    }
}

// ---------------------------------------------------------------------------
// 5) Attention via MFMA. grid (32 bh, 16 rowblocks of 64). 256 thr, 4 waves.
// ---------------------------------------------------------------------------
__global__ __launch_bounds__(256) void attn_k(const unsigned short* __restrict__ hwT,
                                              const float* __restrict__ sl_g,
                                              const float* __restrict__ sr_g,
                                              const unsigned int* __restrict__ rmaxkey,
                                              float* __restrict__ hnew) {
    int bh = blockIdx.x;
    int b = bh >> 2, h = bh & 3;
    int tid = threadIdx.x;
    int wave = tid >> 6, lane = tid & 63;
    int q = lane >> 4, r16 = lane & 15;

    __shared__ float srs[D_];                              // 4 KB
    __shared__ __align__(16) unsigned short Vt[64][136];   // 17 KB, +8 pad
    __shared__ float den_lds[64];

    *(float4*)&srs[tid * 4] = *(const float4*)&sr_g[bh * D_ + tid * 4];

    float rm = kdec(rmaxkey[bh]);
    int row0 = blockIdx.y * 64 + wave * 16;
    float sl = sl_g[bh * D_ + row0 + r16];
    float xm = sl + rm;
    float Mn = fmaxf(xm, ALPHA_ * xm);

    floatx4 acc[4];
#pragma unroll
    for (int i = 0; i < 4; i++) acc[i] = (floatx4)0.f;
    float dsum = 0.f;

    const unsigned short* vbase = hwT + ((size_t)(bh * 64) << 10);

    for (int mc = 0; mc < D_; mc += 128) {
        __syncthreads();
#pragma unroll
        for (int i = 0; i < 4; i++) {
            int s = tid + i * 256;
            int e = s >> 4, part = s & 15;
            *(uint4*)&Vt[e][part * 8] = *(const uint4*)&vbase[((size_t)e << 10) + mc + part * 8];
        }
        __syncthreads();
#pragma unroll
        for (int kk = 0; kk < 128; kk += 32) {
            int m0 = mc + kk + q * 8;
            float4 s0 = *(const float4*)&srs[m0];
            float4 s1 = *(const float4*)&srs[m0 + 4];
            float sr8[8] = {s0.x, s0.y, s0.z, s0.w, s1.x, s1.y, s1.z, s1.w};
            float p[8];
#pragma unroll
            for (int j = 0; j < 8; j++) {
                float x = sl + sr8[j];
                float e = fmaxf(x, ALPHA_ * x);
                float pj = __expf(e - Mn);
                dsum += pj;
                p[j] = pj;
            }
            union { unsigned int u[4]; short8 s8; } cv;
#pragma unroll
            for (int j = 0; j < 4; j++) {
                unsigned int lo = (__float_as_uint(p[2 * j]) + 0x8000u) >> 16;
                unsigned int hi = (__float_as_uint(p[2 * j + 1]) + 0x8000u) & 0xffff0000u;
                cv.u[j] = hi | lo;
            }
#pragma unroll
            for (int ni = 0; ni < 4; ni++) {
                short8 bfr = *(const short8*)&Vt[ni * 16 + r16][kk + q * 8];
                acc[ni] = __builtin_amdgcn_mfma_f32_16x16x32_bf16(cv.s8, bfr, acc[ni], 0, 0, 0);
            }
        }
    }
    dsum += __shfl_xor(dsum, 16);
    dsum += __shfl_xor(dsum, 32);
    if (q == 0) den_lds[wave * 16 + r16] = dsum;
    __syncthreads();
#pragma unroll
    for (int rr = 0; rr < 4; rr++) {
        int rloc = q * 4 + rr;
        float rden = 1.f / den_lds[wave * 16 + rloc];
        size_t grow = (size_t)(b * D_ + blockIdx.y * 64 + wave * 16 + rloc);
#pragma unroll
        for (int ni = 0; ni < 4; ni++) {
            hnew[grow * HID_ + h * OUT_ + ni * 16 + r16] = acc[ni][rr] * rden;
        }
    }
}

// ---------------------------------------------------------------------------
// 6) h = LayerNorm(h + hnew)*g + b. One wave per row, shfl-only reductions.
//    grid 2048 blocks x 256 (4 rows/block).
// ---------------------------------------------------------------------------
__global__ __launch_bounds__(256) void addln_k(float* __restrict__ h,
                                               const float* __restrict__ hn,
                                               const float* __restrict__ g,
                                               const float* __restrict__ bb,
                                               unsigned short* __restrict__ hbf) {
    int wave = threadIdx.x >> 6, lane = threadIdx.x & 63;
    size_t row = (size_t)blockIdx.x * 4 + wave;
    float4 a = *(const float4*)&h[row * HID_ + lane * 4];
    float4 r = *(const float4*)&hn[row * HID_ + lane * 4];
    float4 v = {a.x + r.x, a.y + r.y, a.z + r.z, a.w + r.w};
    float s = v.x + v.y + v.z + v.w;
#pragma unroll
    for (int off = 1; off < 64; off <<= 1) s += __shfl_xor(s, off, 64);
    float mu = s * (1.f / HID_);
    float4 d = {v.x - mu, v.y - mu, v.z - mu, v.w - mu};
    float s2 = d.x * d.x + d.y * d.y + d.z * d.z + d.w * d.w;
#pragma unroll
    for (int off = 1; off < 64; off <<= 1) s2 += __shfl_xor(s2, off, 64);
    float rs = rsqrtf(s2 * (1.f / HID_) + EPS_);
    float4 gg = *(const float4*)&g[lane * 4];
    float4 bbv = *(const float4*)&bb[lane * 4];
    float4 res;
    res.x = d.x * rs * gg.x + bbv.x;
    res.y = d.y * rs * gg.y + bbv.y;
    res.z = d.z * rs * gg.z + bbv.z;
    res.w = d.w * rs * gg.w + bbv.w;
    *(float4*)&h[row * HID_ + lane * 4] = res;
    ushort4 pk = {f2bf(res.x), f2bf(res.y), f2bf(res.z), f2bf(res.w)};
    *(ushort4*)&hbf[row * HID_ + lane * 4] = pk;
}

// ---------------------------------------------------------------------------
extern "C" void kernel_launch(void* const* d_in, const int* in_sizes, int n_in,
                              void* d_out, int out_size, void* d_ws, size_t ws_size,
                              hipStream_t stream) {
    const float* X_obs = (const float*)d_in[0];
    const float* mask  = (const float*)d_in[1];
    const float* W_in  = (const float*)d_in[2];
    const float* b_in  = (const float*)d_in[3];
    const float* gat_W = (const float*)d_in[4];
    const float* gat_a = (const float*)d_in[5];
    const float* ln_g  = (const float*)d_in[6];
    const float* ln_b  = (const float*)d_in[7];
    const float* W_out = (const float*)d_in[8];
    const float* b_out = (const float*)d_in[9];
    float* out = (float*)d_out;

    // Workspace (~29.3 MB):
    //  [0,16M):  Ain bf16 (M x 1024); dead after concat GEMM, reused as
    //            hwT bf16 (4 MB) at 0, hnew fp32 (8 MB) at 4M..12M
    //  [16,24M): hbuf fp32 (M x 256)
    //  [24,28M): hbf bf16 (M x 256)
    //  [28M...): Wt_in, Wcat, WtO (bf16), slb/srb (fp32), rmaxkey (uint[64])
    char* base = (char*)d_ws;
    unsigned short* Ain  = (unsigned short*)base;
    unsigned short* hwT  = (unsigned short*)base;
    float* hnew = (float*)(base + (4u << 20));
    float* hbuf = (float*)(base + (16u << 20));
    unsigned short* hbf   = (unsigned short*)(base + (24u << 20));
    unsigned short* Wt_in = (unsigned short*)(base + (28u << 20));
    unsigned short* Wcat  = Wt_in + (size_t)HID_ * KIN_;        // 256*1024
    unsigned short* WtO   = Wcat + (size_t)NL_ * HID_ * HID_;   // 2*256*256
    float* slb = (float*)(WtO + (size_t)T_ * HID_);             // 32*1024
    float* srb = slb + B_ * NH_ * D_;
    unsigned int* rmaxkey = (unsigned int*)(srb + B_ * NH_ * D_);  // [2][32]

    impute_k<<<DT_ / 1024, 256, 0, stream>>>(X_obs, mask, Ain);
    wprep_k<<<2048, 256, 0, stream>>>(W_in, gat_W, W_out, Wt_in, Wcat, WtO, rmaxkey);

    // h = [X_mean|mask] @ W_in + b_in   (8192x1024)@(1024x256), fp32+bf16 out
    gemm_bf16_k<1><<<dim3(HID_ / 64, M_ / 128), 256, 0, stream>>>(
        Ain, Wt_in, b_in, hbuf, hbf, nullptr, nullptr, nullptr, nullptr,
        HID_, KIN_);

    for (int l = 0; l < NL_; l++) {
        // hW = h @ Wcat[l] -> hwT bf16 + fused s_l/s_r/rmax
        gemm_bf16_k<2><<<dim3(HID_ / 64, M_ / 128), 256, 0, stream>>>(
            hbf, Wcat + (size_t)l * HID_ * HID_, nullptr, nullptr, hwT,
            gat_a + (size_t)l * NH_ * 2 * OUT_, slb, srb, rmaxkey + l * 32,
            HID_, HID_);
        attn_k<<<dim3(B_ * NH_, D_ / 64), 256, 0, stream>>>(
            hwT, slb, srb, rmaxkey + l * 32, hnew);
        addln_k<<<M_ / 4, 256, 0, stream>>>(hbuf, hnew, ln_g + (size_t)l * HID_,
                                            ln_b + (size_t)l * HID_, hbf);
    }

    // out = h @ W_out + b_out  (8192x256)@(256x512), fp32 out
    gemm_bf16_k<0><<<dim3(T_ / 64, M_ / 128), 256, 0, stream>>>(
        hbf, WtO, b_out, out, nullptr, nullptr, nullptr, nullptr, nullptr,
        T_, HID_);
}